// Round 1
// baseline (931.777 us; speedup 1.0000x reference)
//
#include <hip/hip_runtime.h>
#include <hip/hip_bf16.h>
#include <stdint.h>

#define BATCH 64
#define N 1024

static constexpr float QSCALE = 512.0f;
static constexpr float CE = 1.44269504088896340736f / 512.0f; // log2(e)/QSCALE

typedef int   int4v   __attribute__((ext_vector_type(4)));
typedef float float4v __attribute__((ext_vector_type(4)));

// One fused Sinkhorn iteration:
//   R_i = sum_j exp(P0_ij) / S_in_j      (row LSE in scaled domain)
//   S_out_j += sum_i exp(P0_ij) / R_i    (col partials via atomics)
// Grid: 64 batches x 16 blocks (64 rows each). Block: 256 thr = 4 waves,
// each wave owns 16 rows; lane owns 16 consecutive columns.
template<bool FIRST, bool USEQ>
__global__ __launch_bounds__(256) void sink_pass(
    const float* __restrict__ M, short* __restrict__ Q,
    const float* __restrict__ S_in, float* __restrict__ S_out,
    float* __restrict__ U)
{
    __shared__ float csum[N];
    const int tid  = threadIdx.x;
    const int lane = tid & 63;
    const int wave = tid >> 6;
    const int blk  = blockIdx.x;
    const int b    = blk >> 4;                       // batch
    const int rowbase = ((blk & 15) << 6) + (wave << 4);
    const int c0   = lane << 4;                      // first owned column

    for (int k = tid; k < N; k += 256) csum[k] = 0.0f;

    float rcpS[16];
    if (FIRST) {
#pragma unroll
        for (int c = 0; c < 16; ++c) rcpS[c] = 1.0f;
    } else {
        const float4v* sp = (const float4v*)(S_in + b * N + c0);
#pragma unroll
        for (int v = 0; v < 4; ++v) {
            float4v s = sp[v];
#pragma unroll
            for (int e = 0; e < 4; ++e) rcpS[v * 4 + e] = 1.0f / s[e];
        }
    }

    float cacc[16];
#pragma unroll
    for (int c = 0; c < 16; ++c) cacc[c] = 0.0f;

    __syncthreads();

    const size_t mb = ((size_t)b << 20);

    for (int r = 0; r < 16; ++r) {
        const int row = rowbase + r;
        const size_t off = mb + ((size_t)row << 10) + c0;
        float E[16];
        if (FIRST || !USEQ) {
            const float4v* mp = (const float4v*)(M + off);
            float qf[16];
#pragma unroll
            for (int v = 0; v < 4; ++v) {
                float4v m = mp[v];
#pragma unroll
                for (int e = 0; e < 4; ++e) {
                    float p0 = fminf(fmaxf(m[e], -25.0f), 25.0f) * 10.0f;
                    float q = rintf(p0 * QSCALE);
                    qf[v * 4 + e] = fminf(fmaxf(q, -32767.0f), 32767.0f);
                }
            }
            if (FIRST && USEQ) {
                int4v pk[2];
#pragma unroll
                for (int h = 0; h < 2; ++h)
#pragma unroll
                    for (int e = 0; e < 4; ++e) {
                        int lo = (int)qf[h * 8 + e * 2];
                        int hi = (int)qf[h * 8 + e * 2 + 1];
                        pk[h][e] = (lo & 0xffff) | (hi << 16);
                    }
                int4v* qp = (int4v*)(Q + off);
                qp[0] = pk[0]; qp[1] = pk[1];
            }
#pragma unroll
            for (int c = 0; c < 16; ++c) E[c] = exp2f(qf[c] * CE);
        } else {
            const int4v* qp = (const int4v*)(Q + off);
            int4v qa = qp[0], qb = qp[1];
#pragma unroll
            for (int e = 0; e < 4; ++e) {
                int va = qa[e], vb = qb[e];
                E[e * 2]         = exp2f((float)(short)(va & 0xffff) * CE);
                E[e * 2 + 1]     = exp2f((float)(va >> 16) * CE);
                E[8 + e * 2]     = exp2f((float)(short)(vb & 0xffff) * CE);
                E[8 + e * 2 + 1] = exp2f((float)(vb >> 16) * CE);
            }
        }

        float part = 0.0f;
#pragma unroll
        for (int c = 0; c < 16; ++c) part += E[c] * rcpS[c];
#pragma unroll
        for (int s = 32; s > 0; s >>= 1) part += __shfl_xor(part, s, 64);

        if (lane == 0) U[b * N + row] = part;   // R_i (only last pass's matters)
        const float rcpR = 1.0f / part;
#pragma unroll
        for (int c = 0; c < 16; ++c) cacc[c] += E[c] * rcpR;
    }

    // combine 4 waves' col partials in LDS (lane-rotated to avoid bank conflicts)
#pragma unroll
    for (int k = 0; k < 16; ++k) {
        int c = (k + lane) & 15;
        atomicAdd(&csum[c0 + c], cacc[c]);
    }
    __syncthreads();
    for (int k = tid; k < N; k += 256) atomicAdd(&S_out[b * N + k], csum[k]);
}

// out_ij = exp(P0_ij) / (R_i * S_j)
template<bool USEQ>
__global__ __launch_bounds__(256) void sink_final(
    const float* __restrict__ M, const short* __restrict__ Q,
    const float* __restrict__ U, const float* __restrict__ S,
    float* __restrict__ out)
{
    const size_t base = ((size_t)blockIdx.x * 256 + threadIdx.x) << 3;
    const int b   = (int)(base >> 20);
    const int rem = (int)(base & ((1u << 20) - 1));
    const int i   = rem >> 10;
    const int j   = rem & (N - 1);

    const float rcpR = 1.0f / U[b * N + i];
    const float4v* sp = (const float4v*)(S + b * N + j);
    float4v s0 = sp[0], s1 = sp[1];

    float E[8];
    if (USEQ) {
        const int4v* qp = (const int4v*)(Q + base);
        int4v q = qp[0];
#pragma unroll
        for (int e = 0; e < 4; ++e) {
            int v = q[e];
            E[e * 2]     = exp2f((float)(short)(v & 0xffff) * CE);
            E[e * 2 + 1] = exp2f((float)(v >> 16) * CE);
        }
    } else {
        const float4v* mp = (const float4v*)(M + base);
        float4v m0 = mp[0], m1 = mp[1];
#pragma unroll
        for (int e = 0; e < 4; ++e) {
            float p0 = fminf(fmaxf(m0[e], -25.0f), 25.0f) * 10.0f;
            float q  = fminf(fmaxf(rintf(p0 * QSCALE), -32767.0f), 32767.0f);
            E[e] = exp2f(q * CE);
            p0 = fminf(fmaxf(m1[e], -25.0f), 25.0f) * 10.0f;
            q  = fminf(fmaxf(rintf(p0 * QSCALE), -32767.0f), 32767.0f);
            E[4 + e] = exp2f(q * CE);
        }
    }

    float4v o0, o1;
#pragma unroll
    for (int e = 0; e < 4; ++e) {
        o0[e] = E[e]     * rcpR / s0[e];
        o1[e] = E[4 + e] * rcpR / s1[e];
    }
    float4v* op = (float4v*)(out + base);
    op[0] = o0; op[1] = o1;
}

extern "C" void kernel_launch(void* const* d_in, const int* in_sizes, int n_in,
                              void* d_out, int out_size, void* d_ws, size_t ws_size,
                              hipStream_t stream)
{
    const float* M = (const float*)d_in[0];
    float* out = (float*)d_out;

    const size_t QB = (size_t)BATCH * N * N * sizeof(short); // 128 MiB
    const size_t SB = (size_t)BATCH * N * sizeof(float);     // 256 KiB
    char* ws = (char*)d_ws;
    const bool useQ = ws_size >= QB + 11 * SB;

    short* Q  = useQ ? (short*)ws : nullptr;
    float* Sb = (float*)(useQ ? ws + QB : ws);
    float* U  = (float*)((char*)Sb + 10 * SB);

    // S accumulators must start at zero every call (ws is re-poisoned)
    hipMemsetAsync(Sb, 0, 10 * SB, stream);

    dim3 grid(BATCH * 16), blkd(256);
    const size_t BN = (size_t)BATCH * N;
    if (useQ) {
        sink_pass<true, true><<<grid, blkd, 0, stream>>>(M, Q, nullptr, Sb, U);
        for (int t = 2; t <= 10; ++t)
            sink_pass<false, true><<<grid, blkd, 0, stream>>>(
                M, Q, Sb + (t - 2) * BN, Sb + (t - 1) * BN, U);
        sink_final<true><<<dim3(32768), blkd, 0, stream>>>(M, Q, U, Sb + 9 * BN, out);
    } else {
        sink_pass<true, false><<<grid, blkd, 0, stream>>>(M, nullptr, nullptr, Sb, U);
        for (int t = 2; t <= 10; ++t)
            sink_pass<false, false><<<grid, blkd, 0, stream>>>(
                M, nullptr, Sb + (t - 2) * BN, Sb + (t - 1) * BN, U);
        sink_final<false><<<dim3(32768), blkd, 0, stream>>>(M, nullptr, U, Sb + 9 * BN, out);
    }
}